// Round 1
// baseline (251.510 us; speedup 1.0000x reference)
//
#include <hip/hip_runtime.h>

// MySoftBCELoss: per-row l = argmax(target); loss = -mean(t[l]*log(p[l]) + log(1-p[0]))
// p = clamp(sigmoid(logits), 1e-7, 1-1e-7). B=524288 rows, C=64 cols (f32).
//
// R8: latency-stripping round, zero FETCH change. Evidence: softbce_fused is
// ABSENT from rocprof top-5 (all ~78us rows are harness fill/copy), so the
// kernel is <77.8us and the old "kernel=89.6us, 1.3TB/s pin" attribution is
// suspect -- bench 244us decomposes as ~3x78us in-graph harness restore/poison
// + small kernel. This round removes all remaining serialization:
//  (a) drop per-tile __syncthreads: tiles are PER-WAVE; wave-synchronous LDS
//      needs only s_waitcnt lgkmcnt(0) + sched_barrier (rule #18).
//  (b) register double-buffer: prefetch tile k+1's 16 float4 (+ x0) during
//      tile k's scan -- stage latency hides under the argmax scan.
//  (c) x0 gather hoisted one tile ahead (independent of argmax).
// Decision rule: if bench stays >=243us and kernel stays out of top-5, the
// floor is the harness graph (~235us of fill/copy) => ROOFLINE next round.

#define BLOCK 128          // 2 waves; LDS 33280 B/block -> 4 blocks/CU, 8 waves/CU
#define GRID 1024

typedef float floatx4 __attribute__((ext_vector_type(4)));  // native vector for nt-load

constexpr int   C_      = 64;
constexpr int   B_      = 524288;
constexpr int   ROWS_   = 64;     // rows per wave-tile
constexpr int   STRIDE_ = 65;     // padded row stride in floats (2-way bank alias = free)
constexpr int   TILES_  = B_ / ROWS_;   // 8192
constexpr int   NW_     = GRID * 2;     // 2048 waves -> 4 tiles/wave
constexpr int   NT_     = TILES_ / NW_; // 4
constexpr float EPS_    = 1e-7f;

__device__ __forceinline__ float clamp_sig(float x) {
    const float p = 1.0f / (1.0f + __expf(-x));
    return fminf(fmaxf(p, EPS_), 1.0f - EPS_);
}

__device__ __forceinline__ void wave_lds_fence() {
    // Tiles are per-wave: no cross-wave LDS sharing, so no s_barrier needed.
    // lgkmcnt(0) drains this wave's DS ops; "memory" clobber orders the LDS
    // accesses around it; sched_barrier(0) pins codegen (rule #18: hipcc can
    // hoist ops past inline-asm waitcnt otherwise).
    asm volatile("s_waitcnt lgkmcnt(0)" ::: "memory");
    __builtin_amdgcn_sched_barrier(0);
}

__global__ __launch_bounds__(BLOCK) void softbce_fused(
    const float* __restrict__ logits,
    const float* __restrict__ target,
    float* __restrict__ out)
{
    __shared__ float tile[2][ROWS_ * STRIDE_];   // per-wave tiles
    const int lane = threadIdx.x & 63;
    const int wib  = threadIdx.x >> 6;           // wave in block: 0..1
    float* T = tile[wib];

    const int gw = blockIdx.x * 2 + wib;         // global wave id 0..2047
    float acc = 0.0f;

    // ---- prologue: issue tile 0's target loads + x0 gather into registers ----
    floatx4 r[16];
    {
        const int tl0 = (TILES_ - 1) - gw;       // descending order preserved
        const float* src = target + (size_t)(tl0 * ROWS_) * C_;
        #pragma unroll
        for (int i = 0; i < 16; ++i)
            r[i] = __builtin_nontemporal_load((const floatx4*)(src + i * 256 + lane * 4));
    }
    float x0 = __builtin_nontemporal_load(
        logits + (size_t)(((TILES_ - 1) - gw) * ROWS_ + lane) * C_);

    #pragma unroll 1
    for (int k = 0; k < NT_; ++k) {
        const int tl      = (TILES_ - 1) - (gw + k * NW_);
        const int rowBase = tl * ROWS_;

        // WAR fence: previous tile's scan reads must retire before overwrite.
        // (Iteration 0: no outstanding DS ops -> free.)
        wave_lds_fence();

        // ---- drain prefetched regs into LDS (vmcnt waits auto-inserted) ----
        #pragma unroll
        for (int i = 0; i < 16; ++i) {
            const int f  = i * 256 + lane * 4;   // flat float offset in tile
            const int rr = f >> 6;               // row in tile
            const int cc = f & 63;               // col (multiple of 4)
            float* dst = T + rr * STRIDE_ + cc;  // 2-way bank alias = free
            dst[0] = r[i].x; dst[1] = r[i].y; dst[2] = r[i].z; dst[3] = r[i].w;
        }

        const float x0_cur = x0;                 // this tile's logits[row][0]

        // ---- issue NEXT tile's loads now; they fly during the scan ----
        if (k + 1 < NT_) {
            const int tln = (TILES_ - 1) - (gw + (k + 1) * NW_);
            const float* src = target + (size_t)(tln * ROWS_) * C_;
            #pragma unroll
            for (int i = 0; i < 16; ++i)
                r[i] = __builtin_nontemporal_load((const floatx4*)(src + i * 256 + lane * 4));
            x0 = __builtin_nontemporal_load(
                logits + (size_t)(tln * ROWS_ + lane) * C_);
        }

        // RAW fence: this wave's LDS writes visible to all its lanes.
        wave_lds_fence();

        // ---- scan: lane t argmax-scans row t; 4 independent chains ----
        const float* R = T + lane * STRIDE_;     // 2-way bank alias = free
        float v0 = R[0], v1 = R[1], v2 = R[2], v3 = R[3];
        int   i0 = 0,    i1 = 1,    i2 = 2,    i3 = 3;
        #pragma unroll
        for (int kk = 4; kk < 64; kk += 4) {
            const float a = R[kk], b = R[kk+1], c = R[kk+2], d = R[kk+3];
            if (a > v0) { v0 = a; i0 = kk;     }
            if (b > v1) { v1 = b; i1 = kk + 1; }
            if (c > v2) { v2 = c; i2 = kk + 2; }
            if (d > v3) { v3 = d; i3 = kk + 3; }
        }
        // combine chains; exact first-occurrence tie-break (matches jnp.argmax)
        float bv = v0; int bi = i0;
        if (v1 > bv || (v1 == bv && i1 < bi)) { bv = v1; bi = i1; }
        if (v2 > bv || (v2 == bv && i2 < bi)) { bv = v2; bi = i2; }
        if (v3 > bv || (v3 == bv && i3 < bi)) { bv = v3; bi = i3; }

        // ---- dependent xl gather + loss (x0 already in hand) ----
        const size_t grow = (size_t)(rowBase + lane) * C_;
        const float xl = __builtin_nontemporal_load(logits + grow + bi);
        acc += bv * __logf(clamp_sig(xl)) + __logf(1.0f - clamp_sig(x0_cur));
    }

    // wave butterfly, then block combine -> 1024 atomics total
    #pragma unroll
    for (int off = 32; off; off >>= 1) acc += __shfl_xor(acc, off, 64);

    __shared__ float s[2];
    if (lane == 0) s[wib] = acc;
    __syncthreads();
    if (threadIdx.x == 0)
        atomicAdd(out, -(s[0] + s[1]) / (float)B_);  // d_out poison -3e-13, negligible
}

extern "C" void kernel_launch(void* const* d_in, const int* in_sizes, int n_in,
                              void* d_out, int out_size, void* d_ws, size_t ws_size,
                              hipStream_t stream) {
    const float* logits = (const float*)d_in[0];
    const float* target = (const float*)d_in[1];
    float* out = (float*)d_out;

    softbce_fused<<<GRID, BLOCK, 0, stream>>>(logits, target, out);
}